// Round 9
// baseline (44.767 us; speedup 1.0000x reference)
//
#include <hip/hip_runtime.h>
#include <math.h>

typedef _Float16 half8 __attribute__((ext_vector_type(8)));
typedef _Float16 h2 __attribute__((ext_vector_type(2)));
typedef float    f32x4 __attribute__((ext_vector_type(4)));
typedef unsigned int u32;
typedef unsigned long long u64;
typedef unsigned short u16;

#define BIGV 1e30f
#define RSTR 37   // uint2 per ring row (296B). 74 words, gcd(74,32)=2 -> b64 reads 4/bank (conflict-free)

__device__ __forceinline__ u32 dpp_shr1(u32 oldv, u32 src) {
  return (u32)__builtin_amdgcn_update_dpp((int)oldv, (int)src, 0x138, 0xF, 0xF, false);
}
__device__ __forceinline__ float cvtlo(u32 v) {
  union { u16 u; _Float16 h; } c; c.u = (u16)v; return (float)c.h;
}
__device__ __forceinline__ u16 f2h(float f) {
  union { _Float16 h; u16 u; } c; c.h = (_Float16)f; return c.u;
}
__device__ __forceinline__ u32 pkrtz(float a, float b) {
  auto v = __builtin_amdgcn_cvt_pkrtz(a, b);
  union { decltype(v) h; u32 u; } c; c.h = v; return c.u;
}
__device__ __forceinline__ u32 funnel16(u32 hi, u32 lo, u32 sh) {
  return (u32)(((((u64)hi) << 32) | (u64)lo) >> sh);   // v_alignbit
}
__device__ __forceinline__ h2 as_h2(u32 u) { union { u32 u; h2 h; } x; x.u = u; return x.h; }

// Producer/consumer wave specialization, lead-4 + cross-phase prefetch.
// Waves 0-3: MFMA dist tiles -> f16 ring (t-major, 296B row stride).
// Waves 4-7: serial DP chain; phase k prefetches tiles {2k+2,2k+3} (ready since
// phase k-1) then consumes registers loaded last phase -> LDS latency hidden.
__global__ __launch_bounds__(512) void dtw_pc2(
    const float* __restrict__ x,      // (16,16,1024)
    const float* __restrict__ patts,  // (64,16,64)
    float* __restrict__ out,          // (16,64,64,64)
    float w) {
  __shared__ uint4 xsq[2050];            // f16-packed x columns + zero block @2048
  __shared__ uint2 ring2[4 * 64 * RSTR]; // per-pair ring: 64 rows x 296B
  __shared__ float obuf[4 * 1024];       // per-pair output staging
  __shared__ u16   x2h16[1024];          // ||x_t||^2 as f16

  const int tid = threadIdx.x, lane = tid & 63, wv = tid >> 6;
  const int b = blockIdx.x >> 4, pg = blockIdx.x & 15;
  const int role = wv >> 2, pr = wv & 3;
  const int p = pg * 4 + pr;
  const int le = lane & 15, kq = lane >> 4;

  // ---- stage x: coalesced global loads -> f16 LDS (hw index t*16+d) ----
  {
    const float* xb = x + b * (16 * 1024);
    u16* xh = (u16*)xsq;
    for (int idx = tid; idx < 16384; idx += 512) {
      int d = idx >> 10, t = idx & 1023;
      xh[t * 16 + d] = f2h(xb[idx]);
    }
    if (tid == 0) { xsq[2048] = make_uint4(0,0,0,0); xsq[2049] = make_uint4(0,0,0,0); }
    __syncthreads();   // staging pass 1 visible
    for (int t = tid; t < 1024; t += 512) {
      uint4 a0 = xsq[2 * t], a1 = xsq[2 * t + 1];
      float s2 = __builtin_amdgcn_fdot2(as_h2(a0.x), as_h2(a0.x), 0.f, false);
      s2 = __builtin_amdgcn_fdot2(as_h2(a0.y), as_h2(a0.y), s2, false);
      s2 = __builtin_amdgcn_fdot2(as_h2(a0.z), as_h2(a0.z), s2, false);
      s2 = __builtin_amdgcn_fdot2(as_h2(a0.w), as_h2(a0.w), s2, false);
      s2 = __builtin_amdgcn_fdot2(as_h2(a1.x), as_h2(a1.x), s2, false);
      s2 = __builtin_amdgcn_fdot2(as_h2(a1.y), as_h2(a1.y), s2, false);
      s2 = __builtin_amdgcn_fdot2(as_h2(a1.z), as_h2(a1.z), s2, false);
      s2 = __builtin_amdgcn_fdot2(as_h2(a1.w), as_h2(a1.w), s2, false);
      x2h16[t] = f2h(s2);
    }
  }
  __syncthreads();   // B0: staging complete

  if (role == 0) {
    // ================= PRODUCER =================
    half8 bf[4];
    {
      const float* pp = patts + p * (16 * 64);
#pragma unroll
      for (int nb = 0; nb < 4; ++nb) {
        float pv[8]; float part = 0.f;
#pragma unroll
        for (int j = 0; j < 8; ++j) {
          float f = (kq < 2) ? pp[(8 * kq + j) * 64 + nb * 16 + le] : 0.f;
          pv[j] = f; part = fmaf(f, f, part);
        }
        part += __shfl_xor(part, 16, 64);
        part += __shfl_xor(part, 32, 64);
        u32 wd0 = pkrtz(-2.f * pv[0], -2.f * pv[1]);
        u32 wd1 = pkrtz(-2.f * pv[2], -2.f * pv[3]);
        u32 wd2 = pkrtz(-2.f * pv[4], -2.f * pv[5]);
        u32 wd3 = pkrtz(-2.f * pv[6], -2.f * pv[7]);
        if (kq == 2) { wd0 = 0x3C00u | ((u32)f2h(part) << 16); wd1 = 0; wd2 = 0; wd3 = 0; }
        union { uint4 q; half8 h; } bu; bu.q = make_uint4(wd0, wd1, wd2, wd3);
        bf[nb] = bu.h;
      }
    }
    int colp = 8 * kq;
    const int wpbase = pr * (64 * RSTR) + RSTR * le;

#define PRODUCE(T0) { \
    int aidx_ = (kq < 2) ? (2 * ((T0) + le) + kq) : 2048; \
    uint4 aq_ = xsq[aidx_]; \
    u32 x2b_ = (u32)x2h16[(T0) + le]; \
    aq_.x = (kq == 2) ? (x2b_ | 0x3C000000u) : aq_.x; \
    union { uint4 q; half8 h; } au_; au_.q = aq_; \
    int wb_ = wpbase + (colp >> 3); \
    bool mir_ = colp < 32; \
    _Pragma("unroll") \
    for (int nb_ = 0; nb_ < 4; ++nb_) { \
      f32x4 c_ = {0.f, 0.f, 0.f, 0.f}; \
      c_ = __builtin_amdgcn_mfma_f32_16x16x32_f16(au_.h, bf[nb_], c_, 0, 0, 0); \
      float d0_ = __builtin_amdgcn_sqrtf(fmaxf(c_[0], 1e-12f)); \
      float d1_ = __builtin_amdgcn_sqrtf(fmaxf(c_[1], 1e-12f)); \
      float d2_ = __builtin_amdgcn_sqrtf(fmaxf(c_[2], 1e-12f)); \
      float d3_ = __builtin_amdgcn_sqrtf(fmaxf(c_[3], 1e-12f)); \
      uint2 st_; st_.x = pkrtz(d0_, d1_); st_.y = pkrtz(d2_, d3_); \
      ring2[wb_ + (16 * RSTR) * nb_] = st_; \
      if (mir_) ring2[wb_ + (16 * RSTR) * nb_ + 32] = st_; \
    } \
    colp = (colp + 32) & 255; }

    PRODUCE(0); PRODUCE(16); PRODUCE(32); PRODUCE(48);   // lead = 4 tiles
    __syncthreads();   // B1: tiles 0-3 ready
#pragma unroll 1
    for (int k = 0; k < 30; ++k) {       // phase k: produce tiles 2k+4, 2k+5
      PRODUCE(32 * k + 64);
      PRODUCE(32 * k + 80);
      __syncthreads();
    }
    __syncthreads(); __syncthreads(); __syncthreads(); __syncthreads();  // phases 30-33

  } else {
    // ================= CONSUMER =================
    const int rcbase = pr * (64 * RSTR) + RSTR * lane;
    int colc = (((0 - lane) >> 2) << 3) & 255;
    const int ph = (0 - lane) & 3;
    const u32 shv = (u32)((ph & 1) * 16);
    const bool sel2 = (ph & 2) != 0;
    float prev = BIGV, shA = BIGV, shB = BIGV;
    const int bigbits = __float_as_int(BIGV);
    float* obf = obuf + pr * 1024;
    float* obw = obf + lane * 16;
    float* oprow = out + ((b * 64 + p) * 64 + lane) * 64;
    int nextq = 240;

#define LOADQ(Q0,Q1,Q2,Q3,Q4) { int ci_ = rcbase + (colc >> 3); \
    Q0 = ring2[ci_];     Q1 = ring2[ci_ + 1]; Q2 = ring2[ci_ + 2]; \
    Q3 = ring2[ci_ + 3]; Q4 = ring2[ci_ + 4]; \
    colc = (colc + 32) & 255; }

#define SHIFT(curv) { shB = shA; \
    shA = __int_as_float((int)dpp_shr1((u32)bigbits, (u32)__float_as_int(curv))); \
    prev = (curv); }

#define STEP_PRO(S, D) { float dist_ = (D); \
    float m_ = fminf(fminf(prev, shA), shB); \
    float ms_ = (m_ >= 0.5e30f) ? 0.f : m_; \
    float val_ = fmaf(w, ms_, dist_); \
    int t_ = (S) - lane; float cur_ = (t_ >= 0) ? val_ : BIGV; \
    SHIFT(cur_); }

#define STEP_MAIN(S, D) { float dist_ = (D); \
    float m_ = fminf(fminf(prev, shA), shB); \
    float cur_ = fmaf(w, m_, dist_); \
    SHIFT(cur_); }

#define STEP_EPI(S, D) { float dist_ = (D); \
    float m_ = fminf(fminf(prev, shA), shB); \
    float val_ = fmaf(w, m_, dist_); \
    int t_ = (S) - lane; float cur_ = (t_ <= 1023) ? val_ : BIGV; \
    if ((u32)(t_ - 960) < 64u) obw[t_ & 15] = val_; \
    SHIFT(cur_); }

#define FLUSHQ(SQ) { \
    if (nextq < 256 && 4 * nextq + 3 <= (SQ) - 1 - lane - 4) { \
      float4 v_ = *(const float4*)&obf[lane * 16 + ((nextq & 3) << 2)]; \
      *(float4*)(oprow + (nextq << 2) - 960) = v_; ++nextq; \
    } }

#define EXTRACT8(Q0, Q1, Q2, Q3, Q4) \
    u32 W0_ = sel2 ? Q0.y : Q0.x, W1_ = sel2 ? Q1.x : Q0.y, \
        W2_ = sel2 ? Q1.y : Q1.x, W3_ = sel2 ? Q2.x : Q1.y, \
        W4_ = sel2 ? Q2.y : Q2.x, W5_ = sel2 ? Q3.x : Q2.y, \
        W6_ = sel2 ? Q3.y : Q3.x, W7_ = sel2 ? Q4.x : Q3.y, \
        W8_ = sel2 ? Q4.y : Q4.x; \
    u32 A0 = funnel16(W1_, W0_, shv), A1 = funnel16(W2_, W1_, shv), \
        A2 = funnel16(W3_, W2_, shv), A3 = funnel16(W4_, W3_, shv), \
        A4 = funnel16(W5_, W4_, shv), A5 = funnel16(W6_, W5_, shv), \
        A6 = funnel16(W7_, W6_, shv), A7 = funnel16(W8_, W7_, shv);

#define S16(S0, STP) \
    STP((S0)+0,  cvtlo(A0)); STP((S0)+1,  cvtlo(A0 >> 16)); \
    STP((S0)+2,  cvtlo(A1)); STP((S0)+3,  cvtlo(A1 >> 16)); \
    STP((S0)+4,  cvtlo(A2)); STP((S0)+5,  cvtlo(A2 >> 16)); \
    STP((S0)+6,  cvtlo(A3)); STP((S0)+7,  cvtlo(A3 >> 16)); \
    STP((S0)+8,  cvtlo(A4)); STP((S0)+9,  cvtlo(A4 >> 16)); \
    STP((S0)+10, cvtlo(A5)); STP((S0)+11, cvtlo(A5 >> 16)); \
    STP((S0)+12, cvtlo(A6)); STP((S0)+13, cvtlo(A6 >> 16)); \
    STP((S0)+14, cvtlo(A7)); STP((S0)+15, cvtlo(A7 >> 16));

#define SET_PRO(S0)  S16(S0, STEP_PRO)
#define SET_MAIN(S0) S16(S0, STEP_MAIN)
#define SET_EPI(S0) \
    FLUSHQ((S0)+0);  STEP_EPI((S0)+0,  cvtlo(A0)); STEP_EPI((S0)+1,  cvtlo(A0 >> 16)); \
                     STEP_EPI((S0)+2,  cvtlo(A1)); STEP_EPI((S0)+3,  cvtlo(A1 >> 16)); \
    FLUSHQ((S0)+4);  STEP_EPI((S0)+4,  cvtlo(A2)); STEP_EPI((S0)+5,  cvtlo(A2 >> 16)); \
                     STEP_EPI((S0)+6,  cvtlo(A3)); STEP_EPI((S0)+7,  cvtlo(A3 >> 16)); \
    FLUSHQ((S0)+8);  STEP_EPI((S0)+8,  cvtlo(A4)); STEP_EPI((S0)+9,  cvtlo(A4 >> 16)); \
                     STEP_EPI((S0)+10, cvtlo(A5)); STEP_EPI((S0)+11, cvtlo(A5 >> 16)); \
    FLUSHQ((S0)+12); STEP_EPI((S0)+12, cvtlo(A6)); STEP_EPI((S0)+13, cvtlo(A6 >> 16)); \
                     STEP_EPI((S0)+14, cvtlo(A7)); STEP_EPI((S0)+15, cvtlo(A7 >> 16));

    // PHASE: prefetch next pair's quads FIRST (latency hides under 32 DP steps),
    // then consume registers loaded last phase, then barrier.
#define PHASE(C0,C1,C2,C3,C4,C5,C6,C7,C8,C9, L0,L1,L2,L3,L4,L5,L6,L7,L8,L9, S0, SETM) { \
    LOADQ(L0,L1,L2,L3,L4); LOADQ(L5,L6,L7,L8,L9); \
    { EXTRACT8(C0,C1,C2,C3,C4); SETM(S0); } \
    { EXTRACT8(C5,C6,C7,C8,C9); SETM((S0)+16); } \
    __syncthreads(); }

    __syncthreads();   // B1: tiles 0-3 ready
    uint2 a0,a1,a2,a3,a4,a5,a6,a7,a8,a9;
    uint2 b0,b1,b2,b3,b4,b5,b6,b7,b8,b9;
    LOADQ(a0,a1,a2,a3,a4); LOADQ(a5,a6,a7,a8,a9);   // tiles 0,1

    // phases 0,1: s in [0,64), BIG-check + t>=0 mask
    PHASE(a0,a1,a2,a3,a4,a5,a6,a7,a8,a9, b0,b1,b2,b3,b4,b5,b6,b7,b8,b9, 0,  SET_PRO);
    PHASE(b0,b1,b2,b3,b4,b5,b6,b7,b8,b9, a0,a1,a2,a3,a4,a5,a6,a7,a8,a9, 32, SET_PRO);
    // phases 2-29: s in [64,960), lean
#pragma unroll 1
    for (int j = 1; j < 15; ++j) {
      PHASE(a0,a1,a2,a3,a4,a5,a6,a7,a8,a9, b0,b1,b2,b3,b4,b5,b6,b7,b8,b9, 64*j,      SET_MAIN);
      PHASE(b0,b1,b2,b3,b4,b5,b6,b7,b8,b9, a0,a1,a2,a3,a4,a5,a6,a7,a8,a9, 64*j + 32, SET_MAIN);
    }
    // phases 30-33: s in [960,1088), stores + t<=1023 mask
    PHASE(a0,a1,a2,a3,a4,a5,a6,a7,a8,a9, b0,b1,b2,b3,b4,b5,b6,b7,b8,b9, 960,  SET_EPI);
    PHASE(b0,b1,b2,b3,b4,b5,b6,b7,b8,b9, a0,a1,a2,a3,a4,a5,a6,a7,a8,a9, 992,  SET_EPI);
    PHASE(a0,a1,a2,a3,a4,a5,a6,a7,a8,a9, b0,b1,b2,b3,b4,b5,b6,b7,b8,b9, 1024, SET_EPI);
    PHASE(b0,b1,b2,b3,b4,b5,b6,b7,b8,b9, a0,a1,a2,a3,a4,a5,a6,a7,a8,a9, 1056, SET_EPI);

    // drain remaining output quads
#pragma unroll
    for (int rr = 0; rr < 4; ++rr) {
      if (nextq < 256) {
        float4 v_ = *(const float4*)&obf[lane * 16 + ((nextq & 3) << 2)];
        *(float4*)(oprow + (nextq << 2) - 960) = v_; ++nextq;
      }
    }
  }
}

extern "C" void kernel_launch(void* const* d_in, const int* in_sizes, int n_in,
                              void* d_out, int out_size, void* d_ws, size_t ws_size,
                              hipStream_t stream) {
  const float* x     = (const float*)d_in[0];
  const float* patts = (const float*)d_in[1];
  float* out         = (float*)d_out;
  const float w = (float)exp(log(0.1) / 64.0);
  dim3 grid(256), block(512);
  hipLaunchKernelGGL(dtw_pc2, grid, block, 0, stream, x, patts, out, w);
}

// Round 10
// 44.264 us; speedup vs baseline: 1.0114x; 1.0114x over previous
//
#include <hip/hip_runtime.h>
#include <math.h>

typedef _Float16 half8 __attribute__((ext_vector_type(8)));
typedef _Float16 h2 __attribute__((ext_vector_type(2)));
typedef float    f32x4 __attribute__((ext_vector_type(4)));
typedef unsigned int u32;
typedef unsigned short u16;

#define BIGV 1e30f

__device__ __forceinline__ u32 dpp_shr1(u32 oldv, u32 src) {
  return (u32)__builtin_amdgcn_update_dpp((int)oldv, (int)src, 0x138, 0xF, 0xF, false);
}
__device__ __forceinline__ float cvtlo(u32 v) {
  union { u16 u; _Float16 h; } c; c.u = (u16)v; return (float)c.h;
}
__device__ __forceinline__ u16 f2h(float f) {
  union { _Float16 h; u16 u; } c; c.h = (_Float16)f; return c.u;
}
__device__ __forceinline__ u32 pkrtz(float a, float b) {
  auto v = __builtin_amdgcn_cvt_pkrtz(a, b);
  union { decltype(v) h; u32 u; } c; c.h = v; return c.u;
}
__device__ __forceinline__ h2 as_h2(u32 u) { union { u32 u; h2 h; } x; x.u = u; return x.h; }

// P/C wave specialization, 2-wide DP steps, sheared f16 ring (456B rows,
// 112-word window, no mirror), raw s_barrier on consumer side.
__global__ __launch_bounds__(512) void dtw_pc3(
    const float* __restrict__ x,      // (16,16,1024)
    const float* __restrict__ patts,  // (64,16,64)
    float* __restrict__ out,          // (16,64,64,64)
    float wd) {
  __shared__ uint4 xsq[2050];            // f16-packed x columns + zero block @2048
  __shared__ u16   x2h16[1024];          // ||x_t||^2 as f16
  __shared__ uint2 ring2[4 * 64 * 57];   // per-pair ring: 64 rows x 456B

  const int tid = threadIdx.x, lane = tid & 63, wv = tid >> 6;
  const int b = blockIdx.x >> 4, pg = blockIdx.x & 15;
  const int role = wv >> 2, pr = wv & 3;
  const int p = pg * 4 + pr;
  const int le = lane & 15, kq = lane >> 4;

  // ---- stage x ----
  {
    const float* xb = x + b * (16 * 1024);
    u16* xh = (u16*)xsq;
    for (int idx = tid; idx < 16384; idx += 512) {
      int d = idx >> 10, t = idx & 1023;
      xh[t * 16 + d] = f2h(xb[idx]);
    }
    if (tid == 0) { xsq[2048] = make_uint4(0,0,0,0); xsq[2049] = make_uint4(0,0,0,0); }
    __syncthreads();
    for (int t = tid; t < 1024; t += 512) {
      uint4 a0 = xsq[2 * t], a1 = xsq[2 * t + 1];
      float s2 = __builtin_amdgcn_fdot2(as_h2(a0.x), as_h2(a0.x), 0.f, false);
      s2 = __builtin_amdgcn_fdot2(as_h2(a0.y), as_h2(a0.y), s2, false);
      s2 = __builtin_amdgcn_fdot2(as_h2(a0.z), as_h2(a0.z), s2, false);
      s2 = __builtin_amdgcn_fdot2(as_h2(a0.w), as_h2(a0.w), s2, false);
      s2 = __builtin_amdgcn_fdot2(as_h2(a1.x), as_h2(a1.x), s2, false);
      s2 = __builtin_amdgcn_fdot2(as_h2(a1.y), as_h2(a1.y), s2, false);
      s2 = __builtin_amdgcn_fdot2(as_h2(a1.z), as_h2(a1.z), s2, false);
      s2 = __builtin_amdgcn_fdot2(as_h2(a1.w), as_h2(a1.w), s2, false);
      x2h16[t] = f2h(s2);
    }
  }
  __syncthreads();   // B0

  if (role == 0) {
    // ================= PRODUCER =================
    half8 bf[4];
    {
      const float* pp = patts + p * (16 * 64);
#pragma unroll
      for (int nb = 0; nb < 4; ++nb) {
        float pv[8]; float part = 0.f;
#pragma unroll
        for (int j = 0; j < 8; ++j) {
          float f = (kq < 2) ? pp[(8 * kq + j) * 64 + nb * 16 + le] : 0.f;
          pv[j] = f; part = fmaf(f, f, part);
        }
        part += __shfl_xor(part, 16, 64);
        part += __shfl_xor(part, 32, 64);
        u32 wd0 = pkrtz(-2.f * pv[0], -2.f * pv[1]);
        u32 wd1 = pkrtz(-2.f * pv[2], -2.f * pv[3]);
        u32 wd2 = pkrtz(-2.f * pv[4], -2.f * pv[5]);
        u32 wd3 = pkrtz(-2.f * pv[6], -2.f * pv[7]);
        if (kq == 2) { wd0 = 0x3C00u | ((u32)f2h(part) << 16); wd1 = 0; wd2 = 0; wd3 = 0; }
        union { uint4 q; half8 h; } bu; bu.q = make_uint4(wd0, wd1, wd2, wd3);
        bf[nb] = bu.h;
      }
    }
    // write addrs: row = nb*16+le; slot0 = 2kq + (row&~1) (<112); advance +32B/tile, wrap at 448B
    u32 Aa[4], Ee[4];
    const u32 pairbase = (u32)(pr * 29184);
#pragma unroll
    for (int nb = 0; nb < 4; ++nb) {
      int row = nb * 16 + le;
      u32 rb = pairbase + (u32)(row * 456);
      Aa[nb] = rb + (u32)(4 * (2 * kq + (row & ~1)));
      Ee[nb] = rb + 448u;
    }

#define PRODUCE(T0) { \
    int aidx_ = (kq < 2) ? (2 * ((T0) + le) + kq) : 2048; \
    uint4 aq_ = xsq[aidx_]; \
    u32 x2b_ = (u32)x2h16[(T0) + le]; \
    aq_.x = (kq == 2) ? (x2b_ | 0x3C000000u) : aq_.x; \
    union { uint4 q; half8 h; } au_; au_.q = aq_; \
    _Pragma("unroll") \
    for (int nb_ = 0; nb_ < 4; ++nb_) { \
      f32x4 c_ = {0.f, 0.f, 0.f, 0.f}; \
      c_ = __builtin_amdgcn_mfma_f32_16x16x32_f16(au_.h, bf[nb_], c_, 0, 0, 0); \
      float d0_ = __builtin_amdgcn_sqrtf(fmaxf(c_[0], 1e-12f)); \
      float d1_ = __builtin_amdgcn_sqrtf(fmaxf(c_[1], 1e-12f)); \
      float d2_ = __builtin_amdgcn_sqrtf(fmaxf(c_[2], 1e-12f)); \
      float d3_ = __builtin_amdgcn_sqrtf(fmaxf(c_[3], 1e-12f)); \
      uint2 st_; st_.x = pkrtz(d0_, d1_); st_.y = pkrtz(d2_, d3_); \
      *(uint2*)((char*)ring2 + Aa[nb_]) = st_; \
      Aa[nb_] += 32u; if (Aa[nb_] >= Ee[nb_]) Aa[nb_] -= 448u; \
    } }

    PRODUCE(0); PRODUCE(16); PRODUCE(32); PRODUCE(48);   // tiles 0-3 (lead 4)
    __syncthreads();   // B1
#pragma unroll 1
    for (int k = 0; k < 30; ++k) {       // phase k: tiles 2k+4, 2k+5
      PRODUCE(32 * k + 64);
      PRODUCE(32 * k + 80);
      __syncthreads();
    }
    for (int k = 0; k < 6; ++k) __syncthreads();   // idle phases 30-35

  } else {
    // ================= CONSUMER =================
    char* crow = (char*)ring2 + pr * 29184 + lane * 456;
    u32 cb = 0;                              // byte of 4*((16P) mod 112); cycles 0,64,...,384
    const bool oddl = (lane & 1) != 0;
    float prevB = BIGV, sA = BIGV, sB = BIGV, sBo = BIGV;
    const int bigbits = __float_as_int(BIGV);
    float* oprow = out + ((b * 64 + p) * 64 + lane) * 64;
    float* ps = oprow;
    uint2 C0,C1,C2,C3,C4,C5,C6,C7, N0,N1,N2,N3,N4,N5,N6,N7;
    uint2 carry; carry.x = 0; carry.y = 0;

#define DPSTEP(K, WRD, PM, EP) { \
    u32 wrd_ = (WRD); \
    float d0_ = cvtlo(wrd_); float d1_ = cvtlo(wrd_ >> 16); \
    float mA_ = fminf(fminf(prevB, sA), sBo); \
    if (PM) mA_ = (mA_ >= 0.5e30f) ? 0.f : mA_; \
    float vA_ = fmaf(wd, mA_, d0_); \
    float mB_ = fminf(fminf(vA_, sB), sA); \
    float vB_ = fmaf(wd, mB_, d1_); \
    if (PM) { bool act_ = ((K) >= lane); vA_ = act_ ? vA_ : BIGV; vB_ = act_ ? vB_ : BIGV; } \
    if (EP) { if ((u32)((K) - lane - 480) < 32u) \
        *(float2*)(ps + 2 * ((K) & 15)) = make_float2(vA_, vB_); } \
    sBo = sB; \
    sA = __int_as_float((int)dpp_shr1((u32)bigbits, (u32)__float_as_int(vA_))); \
    sB = __int_as_float((int)dpp_shr1((u32)bigbits, (u32)__float_as_int(vB_))); \
    prevB = vB_; }

#define PAIR2(K2, CJ, CJM1, PM, EP) { \
    u32 w0_ = oddl ? (CJM1).y : (CJ).x; \
    u32 w1_ = oddl ? (CJ).x   : (CJ).y; \
    DPSTEP((K2),     w0_, PM, EP); \
    DPSTEP((K2) + 1, w1_, PM, EP); }

#define CLOAD(Q0,Q1,Q2,Q3,Q4,Q5,Q6,Q7) { \
    char* na_ = crow + cb; \
    Q0 = *(uint2*)(na_);      Q1 = *(uint2*)(na_ + 8); \
    Q2 = *(uint2*)(na_ + 16); Q3 = *(uint2*)(na_ + 24); \
    Q4 = *(uint2*)(na_ + 32); Q5 = *(uint2*)(na_ + 40); \
    Q6 = *(uint2*)(na_ + 48); Q7 = *(uint2*)(na_ + 56); \
    cb += 64; if (cb == 448) cb = 0; }

#define PHASE(A0_,A1_,A2_,A3_,A4_,A5_,A6_,A7_, B0_,B1_,B2_,B3_,B4_,B5_,B6_,B7_, K0, PM, EP) { \
    if (EP) ps = oprow + (2 * (K0) - 960) - 2 * lane; \
    CLOAD(B0_,B1_,B2_,B3_,B4_,B5_,B6_,B7_); \
    PAIR2((K0) + 0,  A0_, carry, PM, EP); \
    PAIR2((K0) + 2,  A1_, A0_,   PM, EP); \
    PAIR2((K0) + 4,  A2_, A1_,   PM, EP); \
    PAIR2((K0) + 6,  A3_, A2_,   PM, EP); \
    PAIR2((K0) + 8,  A4_, A3_,   PM, EP); \
    PAIR2((K0) + 10, A5_, A4_,   PM, EP); \
    PAIR2((K0) + 12, A6_, A5_,   PM, EP); \
    PAIR2((K0) + 14, A7_, A6_,   PM, EP); \
    carry = A7_; \
    __builtin_amdgcn_s_barrier(); }

    __builtin_amdgcn_s_barrier();   // B1: tiles 0-3 ready
    CLOAD(C0,C1,C2,C3,C4,C5,C6,C7);   // pairs for phase 0 (tiles 0,1)

    // phases 0-3: prologue (BIG-check + k>=lane mask)
    PHASE(C0,C1,C2,C3,C4,C5,C6,C7, N0,N1,N2,N3,N4,N5,N6,N7, 0,  1, 0);
    PHASE(N0,N1,N2,N3,N4,N5,N6,N7, C0,C1,C2,C3,C4,C5,C6,C7, 16, 1, 0);
    PHASE(C0,C1,C2,C3,C4,C5,C6,C7, N0,N1,N2,N3,N4,N5,N6,N7, 32, 1, 0);
    PHASE(N0,N1,N2,N3,N4,N5,N6,N7, C0,C1,C2,C3,C4,C5,C6,C7, 48, 1, 0);
    // phases 4-29: lean main
#pragma unroll 1
    for (int j = 2; j < 15; ++j) {
      PHASE(C0,C1,C2,C3,C4,C5,C6,C7, N0,N1,N2,N3,N4,N5,N6,N7, 32 * j,      0, 0);
      PHASE(N0,N1,N2,N3,N4,N5,N6,N7, C0,C1,C2,C3,C4,C5,C6,C7, 32 * j + 16, 0, 0);
    }
    // phases 30-35: epilogue (gated stores)
    PHASE(C0,C1,C2,C3,C4,C5,C6,C7, N0,N1,N2,N3,N4,N5,N6,N7, 480, 0, 1);
    PHASE(N0,N1,N2,N3,N4,N5,N6,N7, C0,C1,C2,C3,C4,C5,C6,C7, 496, 0, 1);
    PHASE(C0,C1,C2,C3,C4,C5,C6,C7, N0,N1,N2,N3,N4,N5,N6,N7, 512, 0, 1);
    PHASE(N0,N1,N2,N3,N4,N5,N6,N7, C0,C1,C2,C3,C4,C5,C6,C7, 528, 0, 1);
    PHASE(C0,C1,C2,C3,C4,C5,C6,C7, N0,N1,N2,N3,N4,N5,N6,N7, 544, 0, 1);
    PHASE(N0,N1,N2,N3,N4,N5,N6,N7, C0,C1,C2,C3,C4,C5,C6,C7, 560, 0, 1);
  }
}

extern "C" void kernel_launch(void* const* d_in, const int* in_sizes, int n_in,
                              void* d_out, int out_size, void* d_ws, size_t ws_size,
                              hipStream_t stream) {
  const float* x     = (const float*)d_in[0];
  const float* patts = (const float*)d_in[1];
  float* out         = (float*)d_out;
  const float w = (float)exp(log(0.1) / 64.0);
  dim3 grid(256), block(512);
  hipLaunchKernelGGL(dtw_pc3, grid, block, 0, stream, x, patts, out, w);
}